// Round 6
// baseline (257.945 us; speedup 1.0000x reference)
//
#include <hip/hip_runtime.h>

// Problem constants
constexpr int Bb = 4;     // batch
constexpr int Dd = 256;   // channels
constexpr int Nn = 2048;  // query positions
constexpr int Mm = 2048;  // source positions
constexpr int Hh = 4;     // heads
constexpr int D2 = 512;   // 2*D
constexpr int NT = Bb * Nn;  // 8192 total positions

#define FMAXV 3.402823466e38f

typedef _Float16 half8 __attribute__((ext_vector_type(8)));
typedef _Float16 half4v __attribute__((ext_vector_type(4)));
typedef float f32x4 __attribute__((ext_vector_type(4)));

typedef const __attribute__((address_space(1))) void* gas_p;
typedef __attribute__((address_space(3))) void* las_p;

__device__ __forceinline__ void gload16(const void* g, void* l) {
    __builtin_amdgcn_global_load_lds((gas_p)g, (las_p)l, 16, 0, 0);
}

// ---------------------------------------------------------------------------
// Fused prepack: weights + bitmask + activation transpose (unchanged from R5)
// ---------------------------------------------------------------------------
__global__ __launch_bounds__(256)
void prep_all_kernel(const float* __restrict__ Wq, const float* __restrict__ bq,
                     const float* __restrict__ Wk, const float* __restrict__ bk,
                     const float* __restrict__ Wv, const float* __restrict__ bv,
                     const float* __restrict__ Wm,
                     const float* __restrict__ W1, const float* __restrict__ b1,
                     const float* __restrict__ gamma, const float* __restrict__ beta,
                     const float* __restrict__ rmean, const float* __restrict__ rvar,
                     const float* __restrict__ W2, const float* __restrict__ mask,
                     const float* __restrict__ x, const float* __restrict__ source,
                     _Float16* __restrict__ Wqp, float* __restrict__ bqp,
                     _Float16* __restrict__ Wkvp, float* __restrict__ bkvp,
                     _Float16* __restrict__ Wmp,
                     _Float16* __restrict__ W1p, float* __restrict__ b1f,
                     _Float16* __restrict__ W2p,
                     unsigned long long* __restrict__ bmask,
                     _Float16* __restrict__ Yp, _Float16* __restrict__ Sp) {
    const int r = blockIdx.x, t = threadIdx.x;
    if (r < 256) {
        const int h = r >> 6, d = r & 63, so = d * Hh + h;
        Wqp[r * 256 + t] = (_Float16)Wq[so * 256 + t];
        if (t == 0) bqp[r] = bq[so];
    } else if (r < 768) {
        const int rr = r - 256, part = rr >> 8, o = rr & 255;
        const int h = o >> 6, d = o & 63, so = d * Hh + h;
        const float* Ws = part ? Wv : Wk;
        const float* bs = part ? bv : bk;
        Wkvp[rr * 256 + t] = (_Float16)Ws[so * 256 + t];
        if (t == 0) bkvp[rr] = bs[so];
    } else if (r < 1024) {
        const int o = r - 768;
        const int h = t >> 6, d = t & 63, sk = d * Hh + h;
        Wmp[o * 256 + t] = (_Float16)Wm[o * 256 + sk];
    } else if (r < 1536) {
        const int o = r - 1024;
        const float s = gamma[o] * rsqrtf(rvar[o] + 1e-3f);
        W1p[o * 512 + t]       = (_Float16)(W1[o * 512 + t] * s);
        W1p[o * 512 + t + 256] = (_Float16)(W1[o * 512 + t + 256] * s);
        if (t == 0) b1f[o] = (b1[o] - rmean[o]) * s + beta[o];
    } else if (r < 1792) {
        const int o = r - 1536;
        W2p[o * 512 + t]       = (_Float16)W2[o * 512 + t];
        W2p[o * 512 + t + 256] = (_Float16)W2[o * 512 + t + 256];
    } else if (r < 3840) {
        const int id = r - 1792;               // 0..2047
        const int w = t >> 6, lane = t & 63;
        const int row = id * 4 + w;            // 0..8191
        const float* mrow = mask + (size_t)row * Mm;
        unsigned long long* brow = bmask + (size_t)row * (Mm / 64);
        #pragma unroll 4
        for (int word = 0; word < Mm / 64; ++word) {
            const float v = mrow[word * 64 + lane];
            const unsigned long long bits = __ballot(v > 0.f);
            if (lane == 0) brow[word] = bits;
        }
    } else {
        __shared__ _Float16 Ts[64][72];
        const int px = r - 3840;
        const int n0 = (px & 31) * 64, c0 = ((px >> 5) & 3) * 64;
        const int z = px >> 7, b = z >> 1, which = z & 1;
        const float* src = which ? source : x;
        _Float16* dst = which ? Sp : Yp;
        const int stride = which ? 256 : 512;
        const int cl = t >> 2, np = (t & 3) * 16;
        const float* sp = src + ((size_t)b * Dd + c0 + cl) * Nn + n0 + np;
        #pragma unroll
        for (int i = 0; i < 4; ++i) {
            float4 v = *(const float4*)(sp + i * 4);
            Ts[np + i * 4 + 0][cl] = (_Float16)v.x;
            Ts[np + i * 4 + 1][cl] = (_Float16)v.y;
            Ts[np + i * 4 + 2][cl] = (_Float16)v.z;
            Ts[np + i * 4 + 3][cl] = (_Float16)v.w;
        }
        __syncthreads();
        const int nl = t >> 2, cp = (t & 3) * 16;
        half8 a0 = *(const half8*)&Ts[nl][cp];
        half8 a1 = *(const half8*)&Ts[nl][cp + 8];
        _Float16* dp = dst + ((size_t)b * Nn + n0 + nl) * stride + c0 + cp;
        *(half8*)dp = a0;
        *(half8*)(dp + 8) = a1;
    }
}

// ---------------------------------------------------------------------------
// QKV GEMM (R5 structure, unchanged): BM=128, BN=64, gload_lds staging + XOR
// swizzle. Only used for the fused Q/K/V projection now (modeSel==3).
// ---------------------------------------------------------------------------
__global__ __launch_bounds__(256)
void gemm4w_kernel(const _Float16* __restrict__ A, const _Float16* __restrict__ A2,
                   const _Float16* __restrict__ W, const float* __restrict__ bias,
                   _Float16* __restrict__ dst0, _Float16* __restrict__ dst1,
                   _Float16* __restrict__ dst2, float* __restrict__ dstF,
                   int K, int sA, int sOut, int modeSel, int relu, float oscale) {
    __shared__ __align__(16) _Float16 As[2 * 128 * 64];   // 32 KB
    __shared__ __align__(16) _Float16 Bs[2 * 64 * 64];    // 16 KB
    __shared__ __align__(16) _Float16 Es[4][16][72];      //  9 KB

    const int t = threadIdx.x;
    const int w = t >> 6, lane = t & 63, quad = lane >> 4, l16 = lane & 15;
    const int n0 = blockIdx.x * 128;
    const int og0 = blockIdx.y * 64;

    int mode = 0, oloc0 = og0;
    const _Float16* Ab = A;
    int sAl = sA;
    _Float16* d0 = dst0;
    float osc = oscale;
    if (modeSel == 3) {
        const int part = blockIdx.y >> 2;               // 0=Q, 1=K, 2=V
        if (part == 1)      { Ab = A2; sAl = 256; d0 = dst1; oloc0 = og0 - 256; osc = 1.0f; }
        else if (part == 2) { Ab = A2; sAl = 256; mode = 1; oloc0 = og0 - 512; osc = 1.0f; }
    } else if (modeSel == 2) {
        mode = 2;
    }

    const int srow = t >> 3, sslot = t & 7;
    const int schunk = sslot ^ (srow & 7);

    f32x4 acc[2][4] = {};
    const int nk = K / 64;
    int buf = 0;

    {
        #pragma unroll
        for (int c = 0; c < 4; ++c)
            gload16(Ab + (size_t)(n0 + c * 32 + srow) * sAl + schunk * 8,
                    As + c * 2048 + t * 8);
        #pragma unroll
        for (int c = 0; c < 2; ++c)
            gload16(W + (size_t)(og0 + c * 32 + srow) * K + schunk * 8,
                    Bs + c * 2048 + t * 8);
        __asm__ volatile("s_waitcnt vmcnt(0)" ::: "memory");
        __syncthreads();
    }

    #pragma unroll 1
    for (int kt = 0; kt < nk; ++kt) {
        if (kt + 1 < nk) {
            const int k0 = (kt + 1) * 64, nb = buf ^ 1;
            #pragma unroll
            for (int c = 0; c < 4; ++c)
                gload16(Ab + (size_t)(n0 + c * 32 + srow) * sAl + k0 + schunk * 8,
                        As + nb * 8192 + c * 2048 + t * 8);
            #pragma unroll
            for (int c = 0; c < 2; ++c)
                gload16(W + (size_t)(og0 + c * 32 + srow) * K + k0 + schunk * 8,
                        Bs + nb * 4096 + c * 2048 + t * 8);
        }
        #pragma unroll
        for (int ks = 0; ks < 2; ++ks) {
            const int csw = ((ks * 4 + quad) ^ (l16 & 7)) * 8;
            half8 af[2], bf[4];
            #pragma unroll
            for (int i = 0; i < 2; ++i)
                af[i] = *(const half8*)&As[buf * 8192 + (w * 32 + i * 16 + l16) * 64 + csw];
            #pragma unroll
            for (int j = 0; j < 4; ++j)
                bf[j] = *(const half8*)&Bs[buf * 4096 + (j * 16 + l16) * 64 + csw];
            #pragma unroll
            for (int i = 0; i < 2; ++i)
                #pragma unroll
                for (int j = 0; j < 4; ++j)
                    acc[i][j] = __builtin_amdgcn_mfma_f32_16x16x32_f16(af[i], bf[j], acc[i][j], 0, 0, 0);
        }
        if (kt + 1 < nk) {
            __asm__ volatile("s_waitcnt vmcnt(0)" ::: "memory");
            __syncthreads();
            buf ^= 1;
        }
    }

    float bcol[4];
    #pragma unroll
    for (int j = 0; j < 4; ++j) bcol[j] = bias[og0 + j * 16 + l16];

    if (mode == 0) {
        #pragma unroll
        for (int i = 0; i < 2; ++i) {
            #pragma unroll
            for (int j = 0; j < 4; ++j)
                #pragma unroll
                for (int reg = 0; reg < 4; ++reg) {
                    float v = (acc[i][j][reg] + bcol[j]) * osc;
                    if (relu) v = fmaxf(v, 0.f);
                    Es[w][quad * 4 + reg][j * 16 + l16] = (_Float16)v;
                }
            __asm__ volatile("s_waitcnt lgkmcnt(0)" ::: "memory");
            const int row = lane & 15, oseg = (lane >> 4) * 16;
            half8 e0 = *(const half8*)&Es[w][row][oseg];
            half8 e1 = *(const half8*)&Es[w][row][oseg + 8];
            _Float16* dp = d0 + (size_t)(n0 + w * 32 + i * 16 + row) * sOut + oloc0 + oseg;
            *(half8*)dp = e0;
            *(half8*)(dp + 8) = e1;
            __asm__ volatile("s_waitcnt lgkmcnt(0)" ::: "memory");
        }
    } else if (mode == 1) {
        #pragma unroll
        for (int i = 0; i < 2; ++i) {
            const int ng = n0 + w * 32 + i * 16 + quad * 4;
            const int bidx = ng >> 11, m0 = ng & 2047;
            #pragma unroll
            for (int j = 0; j < 4; ++j) {
                const int o = oloc0 + j * 16 + l16;
                half4v pv;
                #pragma unroll
                for (int reg = 0; reg < 4; ++reg) pv[reg] = (_Float16)(acc[i][j][reg] + bcol[j]);
                *(half4v*)(dst2 + ((size_t)bidx * 256 + o) * (size_t)Mm + m0) = pv;
            }
        }
    } else {
        #pragma unroll
        for (int i = 0; i < 2; ++i) {
            const int ng = n0 + w * 32 + i * 16 + quad * 4;
            const int bidx = ng >> 11, m0 = ng & 2047;
            #pragma unroll
            for (int j = 0; j < 4; ++j) {
                const int o = og0 + j * 16 + l16;
                f32x4 v;
                #pragma unroll
                for (int reg = 0; reg < 4; ++reg) v[reg] = acc[i][j][reg] + bcol[j];
                *(f32x4*)(dstF + ((size_t)bidx * 256 + o) * (size_t)Nn + m0) = v;
            }
        }
    }
}

// ---------------------------------------------------------------------------
// MFMA attention R5 (unchanged): m-split x2, single-buffer LDS, XCD-aware
// grid, static-max softmax with pre-scaled Q, bitmask.
// ---------------------------------------------------------------------------
__global__ __launch_bounds__(256)
void attn_mfma_kernel(const _Float16* __restrict__ Qp, const _Float16* __restrict__ Kp,
                      const _Float16* __restrict__ Vt,
                      const unsigned int* __restrict__ bmask,
                      _Float16* __restrict__ Oa, _Float16* __restrict__ Ob,
                      float* __restrict__ La, float* __restrict__ Lb) {
    __shared__ __align__(16) _Float16 Ks[64][72];
    __shared__ __align__(16) _Float16 Vs[64][72];
    __shared__ __align__(16) _Float16 Ps[4][16][72];

    const int id = blockIdx.x;
    const int xcd = id & 7, loc = id >> 3;
    const int bh = xcd * 2 + (loc >> 6);
    const int sub = loc & 63;
    const int mhalf = sub & 1;
    const int n0 = (sub >> 1) * 64;
    const int b = bh >> 2, h = bh & 3;

    const int t = threadIdx.x;
    const int w = t >> 6, lane = t & 63, quad = lane >> 4, l16 = lane & 15;

    const _Float16* qp = Qp + ((size_t)b * Nn + n0 + w * 16 + l16) * 256 + h * 64 + quad * 8;
    const half8 qa0 = *(const half8*)(qp);
    const half8 qa1 = *(const half8*)(qp + 32);

    const _Float16* Kstg = Kp + (size_t)b * Nn * 256 + h * 64;
    const _Float16* Vstg = Vt + ((size_t)b * 256 + h * 64) * (size_t)Mm;
    const int sr = t >> 2, sc = (t & 3) * 16;

    const unsigned int* bmBase = bmask + ((size_t)b * Nn + n0 + w * 16 + quad * 4) * (Mm / 32);

    _Float16* Od = mhalf ? Ob : Oa;
    float* Ld = mhalf ? Lb : La;
    const int mbeg = mhalf * (Mm / 2);

    float lo[4] = {0.f, 0.f, 0.f, 0.f};
    f32x4 O[4] = {};

    half8 sk0, sk1, sv0, sv1;
    auto stage_load = [&](int m0) {
        const _Float16* ks = Kstg + (size_t)(m0 + sr) * 256 + sc;
        sk0 = *(const half8*)(ks);
        sk1 = *(const half8*)(ks + 8);
        const _Float16* vs = Vstg + (size_t)sr * Mm + m0 + sc;
        sv0 = *(const half8*)(vs);
        sv1 = *(const half8*)(vs + 8);
    };
    auto stage_write = [&]() {
        *(half8*)&Ks[sr][sc]     = sk0;
        *(half8*)&Ks[sr][sc + 8] = sk1;
        *(half8*)&Vs[sr][sc]     = sv0;
        *(half8*)&Vs[sr][sc + 8] = sv1;
    };

    stage_load(mbeg);
    stage_write();
    __syncthreads();

    #pragma unroll 1
    for (int it = 0; it < (Mm / 2) / 64; ++it) {
        const int m0 = mbeg + it * 64;
        if (it < (Mm / 2) / 64 - 1) stage_load(m0 + 64);

        uint2 bmv[4];
        #pragma unroll
        for (int reg = 0; reg < 4; ++reg)
            bmv[reg] = *(const uint2*)(bmBase + (size_t)reg * (Mm / 32) + (m0 >> 5));

        f32x4 S[4];
        #pragma unroll
        for (int mt = 0; mt < 4; ++mt) {
            half8 k0 = *(const half8*)&Ks[mt * 16 + l16][quad * 8];
            half8 k1 = *(const half8*)&Ks[mt * 16 + l16][32 + quad * 8];
            f32x4 z = {0.f, 0.f, 0.f, 0.f};
            z = __builtin_amdgcn_mfma_f32_16x16x32_f16(qa0, k0, z, 0, 0, 0);
            z = __builtin_amdgcn_mfma_f32_16x16x32_f16(qa1, k1, z, 0, 0, 0);
            S[mt] = z;
        }

        float p[4][4];
        #pragma unroll
        for (int reg = 0; reg < 4; ++reg) {
            const unsigned losh = bmv[reg].x >> l16;
            const unsigned hish = bmv[reg].y >> l16;
            p[0][reg] = (losh & 1u)         ? __expf(S[0][reg]) : 0.f;
            p[1][reg] = ((losh >> 16) & 1u) ? __expf(S[1][reg]) : 0.f;
            p[2][reg] = (hish & 1u)         ? __expf(S[2][reg]) : 0.f;
            p[3][reg] = ((hish >> 16) & 1u) ? __expf(S[3][reg]) : 0.f;
        }
        #pragma unroll
        for (int reg = 0; reg < 4; ++reg)
            lo[reg] += (p[0][reg] + p[1][reg]) + (p[2][reg] + p[3][reg]);

        #pragma unroll
        for (int mt = 0; mt < 4; ++mt)
            #pragma unroll
            for (int reg = 0; reg < 4; ++reg)
                Ps[w][quad * 4 + reg][mt * 16 + l16] = (_Float16)p[mt][reg];
        __asm__ volatile("s_waitcnt lgkmcnt(0)" ::: "memory");
        half8 pa0 = *(const half8*)&Ps[w][l16][quad * 8];
        half8 pa1 = *(const half8*)&Ps[w][l16][32 + quad * 8];

        #pragma unroll
        for (int dt = 0; dt < 4; ++dt) {
            half8 v0 = *(const half8*)&Vs[dt * 16 + l16][quad * 8];
            half8 v1 = *(const half8*)&Vs[dt * 16 + l16][32 + quad * 8];
            O[dt] = __builtin_amdgcn_mfma_f32_16x16x32_f16(pa0, v0, O[dt], 0, 0, 0);
            O[dt] = __builtin_amdgcn_mfma_f32_16x16x32_f16(pa1, v1, O[dt], 0, 0, 0);
        }

        if (it < (Mm / 2) / 64 - 1) {
            __syncthreads();
            stage_write();
            __syncthreads();
        }
    }

    #pragma unroll
    for (int reg = 0; reg < 4; ++reg) {
        float s = lo[reg];
        s += __shfl_xor(s, 1);
        s += __shfl_xor(s, 2);
        s += __shfl_xor(s, 4);
        s += __shfl_xor(s, 8);
        lo[reg] = s;
    }

    _Float16* op = Od + ((size_t)b * Nn + n0 + w * 16 + quad * 4) * 256 + h * 64 + l16;
    #pragma unroll
    for (int reg = 0; reg < 4; ++reg)
        #pragma unroll
        for (int dt = 0; dt < 4; ++dt)
            op[(size_t)reg * 256 + dt * 16] = (_Float16)(O[dt][reg] * 0.0625f);
    if (l16 == 0) {
        #pragma unroll
        for (int reg = 0; reg < 4; ++reg)
            Ld[((size_t)b * Nn + n0 + w * 16 + quad * 4 + reg) * 4 + h] = lo[reg] * 0.0625f;
    }
}

// ---------------------------------------------------------------------------
// Inner GEMM stage for the fused MLP: A-fragments from LDS (shared across
// waves), B-fragments streamed from global (L2-hot weights), R1-proven
// two-stage register ping-pong on K. NJ = col-tiles per wave.
// ---------------------------------------------------------------------------
template<int NJ>
__device__ __forceinline__ void mm_stage(const _Float16* As, int sAl,
                                         const _Float16* W, int K,
                                         int oc0, int l16, int quad,
                                         f32x4 (&acc)[NJ]) {
    const _Float16* bRow[NJ];
    #pragma unroll
    for (int j = 0; j < NJ; ++j)
        bRow[j] = W + (size_t)(oc0 + j * 16 + l16) * K + quad * 8;
    const _Float16* aBase = As + l16 * sAl + quad * 8;

    half8 b0[NJ], b1[NJ], a0, a1;
    #pragma unroll
    for (int j = 0; j < NJ; ++j) b0[j] = *(const half8*)(bRow[j]);
    a0 = *(const half8*)(aBase);

    #pragma unroll 1
    for (int k0 = 0; k0 < K; k0 += 64) {
        #pragma unroll
        for (int j = 0; j < NJ; ++j) b1[j] = *(const half8*)(bRow[j] + k0 + 32);
        a1 = *(const half8*)(aBase + k0 + 32);
        #pragma unroll
        for (int j = 0; j < NJ; ++j)
            acc[j] = __builtin_amdgcn_mfma_f32_16x16x32_f16(a0, b0[j], acc[j], 0, 0, 0);
        if (k0 + 64 < K) {
            #pragma unroll
            for (int j = 0; j < NJ; ++j) b0[j] = *(const half8*)(bRow[j] + k0 + 64);
            a0 = *(const half8*)(aBase + k0 + 64);
        }
        #pragma unroll
        for (int j = 0; j < NJ; ++j)
            acc[j] = __builtin_amdgcn_mfma_f32_16x16x32_f16(a1, b1[j], acc[j], 0, 0, 0);
    }
}

// ---------------------------------------------------------------------------
// R6 fused tail: per 16-row block —
//   combine (Oa+Ob)/(La+Lb) -> msgS(LDS), copy x -> y(LDS cols 0..255),
//   msg-proj (K=256) -> y cols 256..511, mlp1+BN+relu (K=512) -> h(LDS),
//   mlp2 (K=512) -> fp32 out [b][256][n].
// Replaces 3 skinny GEMM dispatches + combine (the ~110us pot R0-R5 never
// moved: 10.7GF at ~64TF because N=256-768/K<=512 shapes are prologue- and
// grid-bound). Weights stream from L2 (hot, 0.9MB shared by all blocks).
// Waves split output columns -> A-frags LDS-shared, W read once per block.
// Grid 512 (2 blocks/CU), 256 thr, LDS ~33 KB.
// ---------------------------------------------------------------------------
__global__ __launch_bounds__(256)
void fused_mlp_kernel(const _Float16* __restrict__ Yp,
                      const _Float16* __restrict__ Oa, const _Float16* __restrict__ Ob,
                      const float* __restrict__ La, const float* __restrict__ Lb,
                      const _Float16* __restrict__ Wmp, const float* __restrict__ bm,
                      const _Float16* __restrict__ W1p, const float* __restrict__ b1f,
                      const _Float16* __restrict__ W2p, const float* __restrict__ b2,
                      float* __restrict__ outp) {
    __shared__ __align__(16) _Float16 y[16][520];      // 16640 B (x | msg)
    __shared__ __align__(16) _Float16 hbuf[16 * 520];  // 16640 B (msgS alias, then h)

    const int t = threadIdx.x;
    const int w = t >> 6, lane = t & 63, quad = lane >> 4, l16 = lane & 15;
    const int n0 = blockIdx.x * 16;

    // ---- staging: x -> y[.][0:256]; combined msg -> msgS (= hbuf, stride 264)
    {
        const int row = t >> 4, ch = t & 15, col0 = ch * 16, hh = ch >> 2;
        const size_t gr = (size_t)(n0 + row);
        const _Float16* xs = Yp + gr * 512 + col0;
        *(half8*)&y[row][col0]     = *(const half8*)(xs);
        *(half8*)&y[row][col0 + 8] = *(const half8*)(xs + 8);
        const float inv = 1.0f / (La[gr * 4 + hh] + Lb[gr * 4 + hh]);
        half8 oa0 = *(const half8*)(Oa + gr * 256 + col0);
        half8 oa1 = *(const half8*)(Oa + gr * 256 + col0 + 8);
        half8 ob0 = *(const half8*)(Ob + gr * 256 + col0);
        half8 ob1 = *(const half8*)(Ob + gr * 256 + col0 + 8);
        half8 m0, m1;
        #pragma unroll
        for (int k = 0; k < 8; ++k) {
            m0[k] = (_Float16)(((float)oa0[k] + (float)ob0[k]) * inv);
            m1[k] = (_Float16)(((float)oa1[k] + (float)ob1[k]) * inv);
        }
        *(half8*)&hbuf[row * 264 + col0]     = m0;
        *(half8*)&hbuf[row * 264 + col0 + 8] = m1;
    }
    __syncthreads();

    // ---- stage 1: msg-proj (K=256), wave -> 64 out cols; write y[.][256+..]
    {
        const int oc0 = w * 64;
        f32x4 acc[4] = {};
        mm_stage<4>(hbuf, 264, Wmp, 256, oc0, l16, quad, acc);
        float bcol[4];
        #pragma unroll
        for (int j = 0; j < 4; ++j) bcol[j] = bm[oc0 + j * 16 + l16];
        #pragma unroll
        for (int j = 0; j < 4; ++j)
            #pragma unroll
            for (int reg = 0; reg < 4; ++reg)
                y[quad * 4 + reg][256 + oc0 + j * 16 + l16] =
                    (_Float16)(acc[j][reg] + bcol[j]);
    }
    __syncthreads();   // y complete; all msgS reads done -> hbuf reusable as h

    // ---- stage 2: mlp1 (K=512, BN folded, relu), wave -> 128 cols; write h
    {
        const int oc0 = w * 128;
        f32x4 acc[8] = {};
        mm_stage<8>(&y[0][0], 520, W1p, 512, oc0, l16, quad, acc);
        float bcol[8];
        #pragma unroll
        for (int j = 0; j < 8; ++j) bcol[j] = b1f[oc0 + j * 16 + l16];
        #pragma unroll
        for (int j = 0; j < 8; ++j)
            #pragma unroll
            for (int reg = 0; reg < 4; ++reg)
                hbuf[(quad * 4 + reg) * 520 + oc0 + j * 16 + l16] =
                    (_Float16)fmaxf(acc[j][reg] + bcol[j], 0.f);
    }
    __syncthreads();

    // ---- stage 3: mlp2 (K=512), wave -> 64 cols; fp32 out [b][256][n]
    {
        const int oc0 = w * 64;
        f32x4 acc[4] = {};
        mm_stage<4>(hbuf, 520, W2p, 512, oc0, l16, quad, acc);
        const int m0 = (n0 & 2047) + quad * 4;
        const int bidx = n0 >> 11;
        #pragma unroll
        for (int j = 0; j < 4; ++j) {
            const int o = oc0 + j * 16 + l16;
            const float bc = b2[o];
            f32x4 v;
            #pragma unroll
            for (int reg = 0; reg < 4; ++reg) v[reg] = acc[j][reg] + bc;
            *(f32x4*)(outp + ((size_t)bidx * 256 + o) * (size_t)Nn + m0) = v;
        }
    }
}

// ---------------------------------------------------------------------------
extern "C" void kernel_launch(void* const* d_in, const int* in_sizes, int n_in,
                              void* d_out, int out_size, void* d_ws, size_t ws_size,
                              hipStream_t stream) {
    const float* x      = (const float*)d_in[0];
    const float* source = (const float*)d_in[1];
    const float* mask   = (const float*)d_in[2];
    const float* Wq = (const float*)d_in[3];
    const float* bq = (const float*)d_in[4];
    const float* Wk = (const float*)d_in[5];
    const float* bk = (const float*)d_in[6];
    const float* Wv = (const float*)d_in[7];
    const float* bv = (const float*)d_in[8];
    const float* Wm = (const float*)d_in[9];
    const float* bm = (const float*)d_in[10];
    const float* W1 = (const float*)d_in[11];
    const float* b1 = (const float*)d_in[12];
    const float* gamma = (const float*)d_in[13];
    const float* beta  = (const float*)d_in[14];
    const float* rmean = (const float*)d_in[15];
    const float* rvar  = (const float*)d_in[16];
    const float* W2 = (const float*)d_in[17];
    const float* b2 = (const float*)d_in[18];
    float* outp = (float*)d_out;

    // workspace layout (bytes)
    char* wsb = (char*)d_ws;
    _Float16* Yp   = (_Float16*)wsb;                       // [8192][512]  8 MB
    _Float16* Sp   = (_Float16*)(wsb + (8u << 20));        // [8192][256]  4 MB
    _Float16* Qp   = (_Float16*)(wsb + (12u << 20));       // [8192][256]  4 MB
    _Float16* Kp   = (_Float16*)(wsb + (16u << 20));       // [8192][256]  4 MB
    _Float16* Vt   = (_Float16*)(wsb + (20u << 20));       // [1024][2048] 4 MB
    _Float16* Oa   = (_Float16*)(wsb + (24u << 20));       // [8192][256]  4 MB (O_A partial)
    unsigned long long* bmask = (unsigned long long*)(wsb + (28u << 20));  // 2 MB
    _Float16* Ob = (_Float16*)(wsb + (30u << 20));                          // 4 MB (O_B partial)
    float* La = (float*)(wsb + (34u << 20));                                // 128 KB
    float* Lb = (float*)(wsb + (34u << 20) + (128u << 10));                 // 128 KB
    char* wp = wsb + (36u << 20);
    _Float16* Wqp  = (_Float16*)wp;            wp += 256 * 256 * 2;   // rows 0..255  (Q)
    _Float16* Wkvp = (_Float16*)wp;            wp += 512 * 256 * 2;   // rows 256..767 (K,V)
    _Float16* Wmp  = (_Float16*)wp;            wp += 256 * 256 * 2;
    _Float16* W1p  = (_Float16*)wp;            wp += 512 * 512 * 2;
    _Float16* W2p  = (_Float16*)wp;            wp += 256 * 512 * 2;
    float* bqp  = (float*)wp;                  wp += 256 * 4;
    float* bkvp = (float*)wp;                  wp += 512 * 4;
    float* b1f  = (float*)wp;                  wp += 512 * 4;

    prep_all_kernel<<<4864, 256, 0, stream>>>(
        Wq, bq, Wk, bk, Wv, bv, Wm, W1, b1, gamma, beta, rmean, rvar, W2, mask,
        x, source, Wqp, bqp, Wkvp, bkvp, Wmp, W1p, b1f, W2p, bmask, Yp, Sp);

    // fused Q/K/V projection: (64, 12) blocks of 128x64.
    gemm4w_kernel<<<dim3(NT / 128, 12), 256, 0, stream>>>(
        Yp, Sp, Wqp, bqp, Qp, Kp, Vt, nullptr, 256, 512, 256, 3, 0, 0.125f);

    attn_mfma_kernel<<<1024, 256, 0, stream>>>(Qp, Kp, Vt,
                                               (const unsigned int*)bmask,
                                               Oa, Ob, La, Lb);

    // fused combine + msg-proj + mlp1 + mlp2
    fused_mlp_kernel<<<512, 256, 0, stream>>>(
        Yp, Oa, Ob, La, Lb, Wmp, bm, W1p, b1f, W2p, b2, outp);
}

// Round 7
// 233.321 us; speedup vs baseline: 1.1055x; 1.1055x over previous
//
#include <hip/hip_runtime.h>

// Problem constants
constexpr int Bb = 4;     // batch
constexpr int Dd = 256;   // channels
constexpr int Nn = 2048;  // query positions
constexpr int Mm = 2048;  // source positions
constexpr int Hh = 4;     // heads
constexpr int D2 = 512;   // 2*D
constexpr int NT = Bb * Nn;  // 8192 total positions

#define FMAXV 3.402823466e38f

typedef _Float16 half8 __attribute__((ext_vector_type(8)));
typedef _Float16 half4v __attribute__((ext_vector_type(4)));
typedef float f32x4 __attribute__((ext_vector_type(4)));

typedef const __attribute__((address_space(1))) void* gas_p;
typedef __attribute__((address_space(3))) void* las_p;

__device__ __forceinline__ void gload16(const void* g, void* l) {
    __builtin_amdgcn_global_load_lds((gas_p)g, (las_p)l, 16, 0, 0);
}

// ---------------------------------------------------------------------------
// Fused prepack: weights + bitmask + activation transpose (unchanged)
// ---------------------------------------------------------------------------
__global__ __launch_bounds__(256)
void prep_all_kernel(const float* __restrict__ Wq, const float* __restrict__ bq,
                     const float* __restrict__ Wk, const float* __restrict__ bk,
                     const float* __restrict__ Wv, const float* __restrict__ bv,
                     const float* __restrict__ Wm,
                     const float* __restrict__ W1, const float* __restrict__ b1,
                     const float* __restrict__ gamma, const float* __restrict__ beta,
                     const float* __restrict__ rmean, const float* __restrict__ rvar,
                     const float* __restrict__ W2, const float* __restrict__ mask,
                     const float* __restrict__ x, const float* __restrict__ source,
                     _Float16* __restrict__ Wqp, float* __restrict__ bqp,
                     _Float16* __restrict__ Wkvp, float* __restrict__ bkvp,
                     _Float16* __restrict__ Wmp,
                     _Float16* __restrict__ W1p, float* __restrict__ b1f,
                     _Float16* __restrict__ W2p,
                     unsigned long long* __restrict__ bmask,
                     _Float16* __restrict__ Yp, _Float16* __restrict__ Sp) {
    const int r = blockIdx.x, t = threadIdx.x;
    if (r < 256) {
        const int h = r >> 6, d = r & 63, so = d * Hh + h;
        Wqp[r * 256 + t] = (_Float16)Wq[so * 256 + t];
        if (t == 0) bqp[r] = bq[so];
    } else if (r < 768) {
        const int rr = r - 256, part = rr >> 8, o = rr & 255;
        const int h = o >> 6, d = o & 63, so = d * Hh + h;
        const float* Ws = part ? Wv : Wk;
        const float* bs = part ? bv : bk;
        Wkvp[rr * 256 + t] = (_Float16)Ws[so * 256 + t];
        if (t == 0) bkvp[rr] = bs[so];
    } else if (r < 1024) {
        const int o = r - 768;
        const int h = t >> 6, d = t & 63, sk = d * Hh + h;
        Wmp[o * 256 + t] = (_Float16)Wm[o * 256 + sk];
    } else if (r < 1536) {
        const int o = r - 1024;
        const float s = gamma[o] * rsqrtf(rvar[o] + 1e-3f);
        W1p[o * 512 + t]       = (_Float16)(W1[o * 512 + t] * s);
        W1p[o * 512 + t + 256] = (_Float16)(W1[o * 512 + t + 256] * s);
        if (t == 0) b1f[o] = (b1[o] - rmean[o]) * s + beta[o];
    } else if (r < 1792) {
        const int o = r - 1536;
        W2p[o * 512 + t]       = (_Float16)W2[o * 512 + t];
        W2p[o * 512 + t + 256] = (_Float16)W2[o * 512 + t + 256];
    } else if (r < 3840) {
        const int id = r - 1792;               // 0..2047
        const int w = t >> 6, lane = t & 63;
        const int row = id * 4 + w;            // 0..8191
        const float* mrow = mask + (size_t)row * Mm;
        unsigned long long* brow = bmask + (size_t)row * (Mm / 64);
        #pragma unroll 4
        for (int word = 0; word < Mm / 64; ++word) {
            const float v = mrow[word * 64 + lane];
            const unsigned long long bits = __ballot(v > 0.f);
            if (lane == 0) brow[word] = bits;
        }
    } else {
        __shared__ _Float16 Ts[64][72];
        const int px = r - 3840;
        const int n0 = (px & 31) * 64, c0 = ((px >> 5) & 3) * 64;
        const int z = px >> 7, b = z >> 1, which = z & 1;
        const float* src = which ? source : x;
        _Float16* dst = which ? Sp : Yp;
        const int stride = which ? 256 : 512;
        const int cl = t >> 2, np = (t & 3) * 16;
        const float* sp = src + ((size_t)b * Dd + c0 + cl) * Nn + n0 + np;
        #pragma unroll
        for (int i = 0; i < 4; ++i) {
            float4 v = *(const float4*)(sp + i * 4);
            Ts[np + i * 4 + 0][cl] = (_Float16)v.x;
            Ts[np + i * 4 + 1][cl] = (_Float16)v.y;
            Ts[np + i * 4 + 2][cl] = (_Float16)v.z;
            Ts[np + i * 4 + 3][cl] = (_Float16)v.w;
        }
        __syncthreads();
        const int nl = t >> 2, cp = (t & 3) * 16;
        half8 a0 = *(const half8*)&Ts[nl][cp];
        half8 a1 = *(const half8*)&Ts[nl][cp + 8];
        _Float16* dp = dst + ((size_t)b * Nn + n0 + nl) * stride + c0 + cp;
        *(half8*)dp = a0;
        *(half8*)(dp + 8) = a1;
    }
}

// ---------------------------------------------------------------------------
// R7 GEMM: BM=128 BN=64, gload_lds staging + XOR swizzle. Changes vs R5:
//  - Es dropped; epilogues reuse As buf0 as scratch (final buf==1 for even
//    nk; K is 256 or 512) -> LDS 48 KB -> 3 blocks/CU (was 2).
//  - mode 1 (V) + mode 2 (fp32 out): LDS-transpose epilogue -> coalesced
//    stores (old path: 8-16B stores at 4-8KB lane stride = ~2K L2
//    transactions per block; new: 32-64B contiguous runs).
// ---------------------------------------------------------------------------
__global__ __launch_bounds__(256)
void gemm4w_kernel(const _Float16* __restrict__ A, const _Float16* __restrict__ A2,
                   const _Float16* __restrict__ W, const float* __restrict__ bias,
                   _Float16* __restrict__ dst0, _Float16* __restrict__ dst1,
                   _Float16* __restrict__ dst2, float* __restrict__ dstF,
                   int K, int sA, int sOut, int modeSel, int relu, float oscale) {
    __shared__ __align__(16) _Float16 As[2 * 128 * 64];   // 32 KB
    __shared__ __align__(16) _Float16 Bs[2 * 64 * 64];    // 16 KB

    const int t = threadIdx.x;
    const int w = t >> 6, lane = t & 63, quad = lane >> 4, l16 = lane & 15;
    const int n0 = blockIdx.x * 128;
    const int og0 = blockIdx.y * 64;

    int mode = 0, oloc0 = og0;
    const _Float16* Ab = A;
    int sAl = sA;
    _Float16* d0 = dst0;
    float osc = oscale;
    if (modeSel == 3) {
        const int part = blockIdx.y >> 2;               // 0=Q, 1=K, 2=V
        if (part == 1)      { Ab = A2; sAl = 256; d0 = dst1; oloc0 = og0 - 256; osc = 1.0f; }
        else if (part == 2) { Ab = A2; sAl = 256; mode = 1; oloc0 = og0 - 512; osc = 1.0f; }
    } else if (modeSel == 2) {
        mode = 2;
    }

    const int srow = t >> 3, sslot = t & 7;
    const int schunk = sslot ^ (srow & 7);

    f32x4 acc[2][4] = {};
    const int nk = K / 64;
    int buf = 0;

    {
        #pragma unroll
        for (int c = 0; c < 4; ++c)
            gload16(Ab + (size_t)(n0 + c * 32 + srow) * sAl + schunk * 8,
                    As + c * 2048 + t * 8);
        #pragma unroll
        for (int c = 0; c < 2; ++c)
            gload16(W + (size_t)(og0 + c * 32 + srow) * K + schunk * 8,
                    Bs + c * 2048 + t * 8);
        __asm__ volatile("s_waitcnt vmcnt(0)" ::: "memory");
        __syncthreads();
    }

    #pragma unroll 1
    for (int kt = 0; kt < nk; ++kt) {
        if (kt + 1 < nk) {
            const int k0 = (kt + 1) * 64, nb = buf ^ 1;
            #pragma unroll
            for (int c = 0; c < 4; ++c)
                gload16(Ab + (size_t)(n0 + c * 32 + srow) * sAl + k0 + schunk * 8,
                        As + nb * 8192 + c * 2048 + t * 8);
            #pragma unroll
            for (int c = 0; c < 2; ++c)
                gload16(W + (size_t)(og0 + c * 32 + srow) * K + k0 + schunk * 8,
                        Bs + nb * 4096 + c * 2048 + t * 8);
        }
        #pragma unroll
        for (int ks = 0; ks < 2; ++ks) {
            const int csw = ((ks * 4 + quad) ^ (l16 & 7)) * 8;
            half8 af[2], bf[4];
            #pragma unroll
            for (int i = 0; i < 2; ++i)
                af[i] = *(const half8*)&As[buf * 8192 + (w * 32 + i * 16 + l16) * 64 + csw];
            #pragma unroll
            for (int j = 0; j < 4; ++j)
                bf[j] = *(const half8*)&Bs[buf * 4096 + (j * 16 + l16) * 64 + csw];
            #pragma unroll
            for (int i = 0; i < 2; ++i)
                #pragma unroll
                for (int j = 0; j < 4; ++j)
                    acc[i][j] = __builtin_amdgcn_mfma_f32_16x16x32_f16(af[i], bf[j], acc[i][j], 0, 0, 0);
        }
        if (kt + 1 < nk) {
            __asm__ volatile("s_waitcnt vmcnt(0)" ::: "memory");
            __syncthreads();
            buf ^= 1;
        }
    }

    float bcol[4];
    #pragma unroll
    for (int j = 0; j < 4; ++j) bcol[j] = bias[og0 + j * 16 + l16];

    if (mode == 0) {
        // per-wave transpose scratch in As buf0 (free: final buf==1, nk even)
        _Float16* Escr = As + w * 2048;
        #pragma unroll
        for (int i = 0; i < 2; ++i) {
            #pragma unroll
            for (int j = 0; j < 4; ++j)
                #pragma unroll
                for (int reg = 0; reg < 4; ++reg) {
                    float v = (acc[i][j][reg] + bcol[j]) * osc;
                    if (relu) v = fmaxf(v, 0.f);
                    Escr[(quad * 4 + reg) * 72 + j * 16 + l16] = (_Float16)v;
                }
            __asm__ volatile("s_waitcnt lgkmcnt(0)" ::: "memory");
            const int row = lane & 15, oseg = (lane >> 4) * 16;
            half8 e0 = *(const half8*)&Escr[row * 72 + oseg];
            half8 e1 = *(const half8*)&Escr[row * 72 + oseg + 8];
            _Float16* dp = d0 + (size_t)(n0 + w * 32 + i * 16 + row) * sOut + oloc0 + oseg;
            *(half8*)dp = e0;
            *(half8*)(dp + 8) = e1;
            __asm__ volatile("s_waitcnt lgkmcnt(0)" ::: "memory");
        }
    } else if (mode == 1) {
        // V: scr[c][m] (swizzled) in As buf0, then coalesced 32B stores
        #pragma unroll
        for (int i = 0; i < 2; ++i)
            #pragma unroll
            for (int j = 0; j < 4; ++j) {
                const int c = j * 16 + l16;
                const int mloc = w * 32 + i * 16 + quad * 4;
                const int sw = l16 * 8;                     // (c&15)*8
                half4v pv;
                #pragma unroll
                for (int reg = 0; reg < 4; ++reg)
                    pv[reg] = (_Float16)(acc[i][j][reg] + bcol[j]);
                *(half4v*)&As[c * 128 + (mloc ^ sw)] = pv;
            }
        __syncthreads();
        const int n0m = n0 & 2047, bidx = n0 >> 11;
        #pragma unroll
        for (int r = 0; r < 2; ++r) {
            const int c = (t >> 3) + r * 32;
            const int mch = (t & 7) * 16;
            const int sw = (c & 15) * 8;
            half8 v0 = *(const half8*)&As[c * 128 + (mch ^ sw)];
            half8 v1 = *(const half8*)&As[c * 128 + ((mch + 8) ^ sw)];
            _Float16* dp = dst2 + ((size_t)bidx * 256 + oloc0 + c) * (size_t)Mm + n0m + mch;
            *(half8*)dp = v0;
            *(half8*)(dp + 8) = v1;
        }
    } else {
        // fp32 out: scr[c][m] fp32 (32 KB = whole As; barrier first)
        __syncthreads();
        float* scr = (float*)As;
        #pragma unroll
        for (int i = 0; i < 2; ++i)
            #pragma unroll
            for (int j = 0; j < 4; ++j) {
                const int c = j * 16 + l16;
                const int mloc = w * 32 + i * 16 + quad * 4;
                const int sw = (c & 7) * 4;
                f32x4 v;
                #pragma unroll
                for (int reg = 0; reg < 4; ++reg) v[reg] = acc[i][j][reg] + bcol[j];
                *(f32x4*)&scr[c * 128 + (mloc ^ sw)] = v;
            }
        __syncthreads();
        const int n0m = n0 & 2047, bidx = n0 >> 11;
        #pragma unroll
        for (int r = 0; r < 2; ++r) {
            const int c = (t >> 3) + r * 32;
            const int mch = (t & 7) * 16;
            const int sw = (c & 7) * 4;
            float* dp = dstF + ((size_t)bidx * 256 + og0 + c) * (size_t)Nn + n0m + mch;
            #pragma unroll
            for (int k = 0; k < 4; ++k)
                *(f32x4*)(dp + k * 4) = *(const f32x4*)&scr[c * 128 + ((mch + k * 4) ^ sw)];
        }
    }
}

// ---------------------------------------------------------------------------
// MFMA attention R5 (unchanged): m-split x2, single-buffer LDS, XCD-aware
// grid, static-max softmax with pre-scaled Q, bitmask.
// ---------------------------------------------------------------------------
__global__ __launch_bounds__(256)
void attn_mfma_kernel(const _Float16* __restrict__ Qp, const _Float16* __restrict__ Kp,
                      const _Float16* __restrict__ Vt,
                      const unsigned int* __restrict__ bmask,
                      _Float16* __restrict__ Oa, _Float16* __restrict__ Ob,
                      float* __restrict__ La, float* __restrict__ Lb) {
    __shared__ __align__(16) _Float16 Ks[64][72];
    __shared__ __align__(16) _Float16 Vs[64][72];
    __shared__ __align__(16) _Float16 Ps[4][16][72];

    const int id = blockIdx.x;
    const int xcd = id & 7, loc = id >> 3;
    const int bh = xcd * 2 + (loc >> 6);
    const int sub = loc & 63;
    const int mhalf = sub & 1;
    const int n0 = (sub >> 1) * 64;
    const int b = bh >> 2, h = bh & 3;

    const int t = threadIdx.x;
    const int w = t >> 6, lane = t & 63, quad = lane >> 4, l16 = lane & 15;

    const _Float16* qp = Qp + ((size_t)b * Nn + n0 + w * 16 + l16) * 256 + h * 64 + quad * 8;
    const half8 qa0 = *(const half8*)(qp);
    const half8 qa1 = *(const half8*)(qp + 32);

    const _Float16* Kstg = Kp + (size_t)b * Nn * 256 + h * 64;
    const _Float16* Vstg = Vt + ((size_t)b * 256 + h * 64) * (size_t)Mm;
    const int sr = t >> 2, sc = (t & 3) * 16;

    const unsigned int* bmBase = bmask + ((size_t)b * Nn + n0 + w * 16 + quad * 4) * (Mm / 32);

    _Float16* Od = mhalf ? Ob : Oa;
    float* Ld = mhalf ? Lb : La;
    const int mbeg = mhalf * (Mm / 2);

    float lo[4] = {0.f, 0.f, 0.f, 0.f};
    f32x4 O[4] = {};

    half8 sk0, sk1, sv0, sv1;
    auto stage_load = [&](int m0) {
        const _Float16* ks = Kstg + (size_t)(m0 + sr) * 256 + sc;
        sk0 = *(const half8*)(ks);
        sk1 = *(const half8*)(ks + 8);
        const _Float16* vs = Vstg + (size_t)sr * Mm + m0 + sc;
        sv0 = *(const half8*)(vs);
        sv1 = *(const half8*)(vs + 8);
    };
    auto stage_write = [&]() {
        *(half8*)&Ks[sr][sc]     = sk0;
        *(half8*)&Ks[sr][sc + 8] = sk1;
        *(half8*)&Vs[sr][sc]     = sv0;
        *(half8*)&Vs[sr][sc + 8] = sv1;
    };

    stage_load(mbeg);
    stage_write();
    __syncthreads();

    #pragma unroll 1
    for (int it = 0; it < (Mm / 2) / 64; ++it) {
        const int m0 = mbeg + it * 64;
        if (it < (Mm / 2) / 64 - 1) stage_load(m0 + 64);

        uint2 bmv[4];
        #pragma unroll
        for (int reg = 0; reg < 4; ++reg)
            bmv[reg] = *(const uint2*)(bmBase + (size_t)reg * (Mm / 32) + (m0 >> 5));

        f32x4 S[4];
        #pragma unroll
        for (int mt = 0; mt < 4; ++mt) {
            half8 k0 = *(const half8*)&Ks[mt * 16 + l16][quad * 8];
            half8 k1 = *(const half8*)&Ks[mt * 16 + l16][32 + quad * 8];
            f32x4 z = {0.f, 0.f, 0.f, 0.f};
            z = __builtin_amdgcn_mfma_f32_16x16x32_f16(qa0, k0, z, 0, 0, 0);
            z = __builtin_amdgcn_mfma_f32_16x16x32_f16(qa1, k1, z, 0, 0, 0);
            S[mt] = z;
        }

        float p[4][4];
        #pragma unroll
        for (int reg = 0; reg < 4; ++reg) {
            const unsigned losh = bmv[reg].x >> l16;
            const unsigned hish = bmv[reg].y >> l16;
            p[0][reg] = (losh & 1u)         ? __expf(S[0][reg]) : 0.f;
            p[1][reg] = ((losh >> 16) & 1u) ? __expf(S[1][reg]) : 0.f;
            p[2][reg] = (hish & 1u)         ? __expf(S[2][reg]) : 0.f;
            p[3][reg] = ((hish >> 16) & 1u) ? __expf(S[3][reg]) : 0.f;
        }
        #pragma unroll
        for (int reg = 0; reg < 4; ++reg)
            lo[reg] += (p[0][reg] + p[1][reg]) + (p[2][reg] + p[3][reg]);

        #pragma unroll
        for (int mt = 0; mt < 4; ++mt)
            #pragma unroll
            for (int reg = 0; reg < 4; ++reg)
                Ps[w][quad * 4 + reg][mt * 16 + l16] = (_Float16)p[mt][reg];
        __asm__ volatile("s_waitcnt lgkmcnt(0)" ::: "memory");
        half8 pa0 = *(const half8*)&Ps[w][l16][quad * 8];
        half8 pa1 = *(const half8*)&Ps[w][l16][32 + quad * 8];

        #pragma unroll
        for (int dt = 0; dt < 4; ++dt) {
            half8 v0 = *(const half8*)&Vs[dt * 16 + l16][quad * 8];
            half8 v1 = *(const half8*)&Vs[dt * 16 + l16][32 + quad * 8];
            O[dt] = __builtin_amdgcn_mfma_f32_16x16x32_f16(pa0, v0, O[dt], 0, 0, 0);
            O[dt] = __builtin_amdgcn_mfma_f32_16x16x32_f16(pa1, v1, O[dt], 0, 0, 0);
        }

        if (it < (Mm / 2) / 64 - 1) {
            __syncthreads();
            stage_write();
            __syncthreads();
        }
    }

    #pragma unroll
    for (int reg = 0; reg < 4; ++reg) {
        float s = lo[reg];
        s += __shfl_xor(s, 1);
        s += __shfl_xor(s, 2);
        s += __shfl_xor(s, 4);
        s += __shfl_xor(s, 8);
        lo[reg] = s;
    }

    _Float16* op = Od + ((size_t)b * Nn + n0 + w * 16 + quad * 4) * 256 + h * 64 + l16;
    #pragma unroll
    for (int reg = 0; reg < 4; ++reg)
        #pragma unroll
        for (int dt = 0; dt < 4; ++dt)
            op[(size_t)reg * 256 + dt * 16] = (_Float16)(O[dt][reg] * 0.0625f);
    if (l16 == 0) {
        #pragma unroll
        for (int reg = 0; reg < 4; ++reg)
            Ld[((size_t)b * Nn + n0 + w * 16 + quad * 4 + reg) * 4 + h] = lo[reg] * 0.0625f;
    }
}

// ---------------------------------------------------------------------------
// R7: msg-projection with the combine FUSED into the A-staging path
// (reg-staged: load Oa/Ob + 1/(La+Lb), combine, ds_write; B via gload_lds).
// Replaces combine_kernel + msg gemm: one dispatch fewer, 8 MB less HBM.
// K=256 fixed, out -> Yp cols 256..511 (sOut 512). Grid (64, 4).
// ---------------------------------------------------------------------------
__global__ __launch_bounds__(256)
void gemm_msg_kernel(const _Float16* __restrict__ Oa, const _Float16* __restrict__ Ob,
                     const float* __restrict__ La, const float* __restrict__ Lb,
                     const _Float16* __restrict__ W, const float* __restrict__ bias,
                     _Float16* __restrict__ dst) {
    __shared__ __align__(16) _Float16 As[2 * 128 * 64];   // 32 KB
    __shared__ __align__(16) _Float16 Bs[2 * 64 * 64];    // 16 KB

    const int t = threadIdx.x;
    const int w = t >> 6, lane = t & 63, quad = lane >> 4, l16 = lane & 15;
    const int n0 = blockIdx.x * 128;
    const int og0 = blockIdx.y * 64;
    const int srow = t >> 3, sslot = t & 7;
    const int schunk = sslot ^ (srow & 7);
    constexpr int K = 256;

    f32x4 acc[2][4] = {};

    half8 oa[4], ob[4];
    float inv[4];

    auto loadA = [&](int k0) {             // issue-early (T14)
        const int h = k0 >> 6;
        #pragma unroll
        for (int c = 0; c < 4; ++c) {
            const size_t row = (size_t)(n0 + c * 32 + srow);
            oa[c] = *(const half8*)(Oa + row * 256 + k0 + schunk * 8);
            ob[c] = *(const half8*)(Ob + row * 256 + k0 + schunk * 8);
            inv[c] = 1.0f / (La[row * 4 + h] + Lb[row * 4 + h]);
        }
    };
    auto writeA = [&](int nb) {            // write-late
        #pragma unroll
        for (int c = 0; c < 4; ++c) {
            half8 m;
            #pragma unroll
            for (int k = 0; k < 8; ++k)
                m[k] = (_Float16)(((float)oa[c][k] + (float)ob[c][k]) * inv[c]);
            *(half8*)&As[nb * 8192 + c * 2048 + t * 8] = m;
        }
    };
    auto loadB = [&](int k0, int nb) {
        #pragma unroll
        for (int c = 0; c < 2; ++c)
            gload16(W + (size_t)(og0 + c * 32 + srow) * K + k0 + schunk * 8,
                    Bs + nb * 4096 + c * 2048 + t * 8);
    };

    loadA(0);
    loadB(0, 0);
    writeA(0);
    __asm__ volatile("s_waitcnt vmcnt(0)" ::: "memory");
    __syncthreads();

    int buf = 0;
    #pragma unroll 1
    for (int kt = 0; kt < 4; ++kt) {
        if (kt < 3) {
            loadA((kt + 1) * 64);          // latency hides under MFMAs below
            loadB((kt + 1) * 64, buf ^ 1);
        }
        #pragma unroll
        for (int ks = 0; ks < 2; ++ks) {
            const int csw = ((ks * 4 + quad) ^ (l16 & 7)) * 8;
            half8 af[2], bf[4];
            #pragma unroll
            for (int i = 0; i < 2; ++i)
                af[i] = *(const half8*)&As[buf * 8192 + (w * 32 + i * 16 + l16) * 64 + csw];
            #pragma unroll
            for (int j = 0; j < 4; ++j)
                bf[j] = *(const half8*)&Bs[buf * 4096 + (j * 16 + l16) * 64 + csw];
            #pragma unroll
            for (int i = 0; i < 2; ++i)
                #pragma unroll
                for (int j = 0; j < 4; ++j)
                    acc[i][j] = __builtin_amdgcn_mfma_f32_16x16x32_f16(af[i], bf[j], acc[i][j], 0, 0, 0);
        }
        if (kt < 3) {
            writeA(buf ^ 1);
            __asm__ volatile("s_waitcnt vmcnt(0)" ::: "memory");
            __syncthreads();
            buf ^= 1;
        }
    }

    float bcol[4];
    #pragma unroll
    for (int j = 0; j < 4; ++j) bcol[j] = bias[og0 + j * 16 + l16];

    _Float16* Escr = As + w * 2048;        // buf0 scratch (final buf==1)
    #pragma unroll
    for (int i = 0; i < 2; ++i) {
        #pragma unroll
        for (int j = 0; j < 4; ++j)
            #pragma unroll
            for (int reg = 0; reg < 4; ++reg)
                Escr[(quad * 4 + reg) * 72 + j * 16 + l16] =
                    (_Float16)(acc[i][j][reg] + bcol[j]);
        __asm__ volatile("s_waitcnt lgkmcnt(0)" ::: "memory");
        const int row = lane & 15, oseg = (lane >> 4) * 16;
        half8 e0 = *(const half8*)&Escr[row * 72 + oseg];
        half8 e1 = *(const half8*)&Escr[row * 72 + oseg + 8];
        _Float16* dp = dst + (size_t)(n0 + w * 32 + i * 16 + row) * 512 + og0 + oseg;
        *(half8*)dp = e0;
        *(half8*)(dp + 8) = e1;
        __asm__ volatile("s_waitcnt lgkmcnt(0)" ::: "memory");
    }
}

// ---------------------------------------------------------------------------
extern "C" void kernel_launch(void* const* d_in, const int* in_sizes, int n_in,
                              void* d_out, int out_size, void* d_ws, size_t ws_size,
                              hipStream_t stream) {
    const float* x      = (const float*)d_in[0];
    const float* source = (const float*)d_in[1];
    const float* mask   = (const float*)d_in[2];
    const float* Wq = (const float*)d_in[3];
    const float* bq = (const float*)d_in[4];
    const float* Wk = (const float*)d_in[5];
    const float* bk = (const float*)d_in[6];
    const float* Wv = (const float*)d_in[7];
    const float* bv = (const float*)d_in[8];
    const float* Wm = (const float*)d_in[9];
    const float* bm = (const float*)d_in[10];
    const float* W1 = (const float*)d_in[11];
    const float* b1 = (const float*)d_in[12];
    const float* gamma = (const float*)d_in[13];
    const float* beta  = (const float*)d_in[14];
    const float* rmean = (const float*)d_in[15];
    const float* rvar  = (const float*)d_in[16];
    const float* W2 = (const float*)d_in[17];
    const float* b2 = (const float*)d_in[18];
    float* outp = (float*)d_out;

    // workspace layout (bytes)
    char* wsb = (char*)d_ws;
    _Float16* Yp   = (_Float16*)wsb;                       // [8192][512]  8 MB
    _Float16* Sp   = (_Float16*)(wsb + (8u << 20));        // [8192][256]  4 MB
    _Float16* Qp   = (_Float16*)(wsb + (12u << 20));       // [8192][256]  4 MB
    _Float16* Kp   = (_Float16*)(wsb + (16u << 20));       // [8192][256]  4 MB
    _Float16* Vt   = (_Float16*)(wsb + (20u << 20));       // [1024][2048] 4 MB
    _Float16* Oa   = (_Float16*)(wsb + (24u << 20));       // [8192][256]  4 MB (O_A partial)
    _Float16* Hp   = (_Float16*)(wsb + (28u << 20));       // [8192][512]  8 MB (mlp1 out)
    // transients (dead before mlp1 writes Hp):
    unsigned long long* bmask = (unsigned long long*)(wsb + (28u << 20));  // 2 MB
    _Float16* Ob = (_Float16*)(wsb + (30u << 20));                          // 4 MB (O_B partial)
    float* La = (float*)(wsb + (34u << 20));                                // 128 KB
    float* Lb = (float*)(wsb + (34u << 20) + (128u << 10));                 // 128 KB
    char* wp = wsb + (36u << 20);
    _Float16* Wqp  = (_Float16*)wp;            wp += 256 * 256 * 2;   // rows 0..255  (Q)
    _Float16* Wkvp = (_Float16*)wp;            wp += 512 * 256 * 2;   // rows 256..767 (K,V)
    _Float16* Wmp  = (_Float16*)wp;            wp += 256 * 256 * 2;
    _Float16* W1p  = (_Float16*)wp;            wp += 512 * 512 * 2;
    _Float16* W2p  = (_Float16*)wp;            wp += 256 * 512 * 2;
    float* bqp  = (float*)wp;                  wp += 256 * 4;
    float* bkvp = (float*)wp;                  wp += 512 * 4;
    float* b1f  = (float*)wp;                  wp += 512 * 4;

    prep_all_kernel<<<4864, 256, 0, stream>>>(
        Wq, bq, Wk, bk, Wv, bv, Wm, W1, b1, gamma, beta, rmean, rvar, W2, mask,
        x, source, Wqp, bqp, Wkvp, bkvp, Wmp, W1p, b1f, W2p, bmask, Yp, Sp);

    // fused Q/K/V projection: (64, 12) blocks of 128x64.
    gemm4w_kernel<<<dim3(NT / 128, 12), 256, 0, stream>>>(
        Yp, Sp, Wqp, bqp, Qp, Kp, Vt, nullptr, 256, 512, 256, 3, 0, 0.125f);

    attn_mfma_kernel<<<1024, 256, 0, stream>>>(Qp, Kp, Vt,
                                               (const unsigned int*)bmask,
                                               Oa, Ob, La, Lb);

    // combine + msg projection fused: out -> Yp cols 256..511
    gemm_msg_kernel<<<dim3(NT / 128, 4), 256, 0, stream>>>(
        Oa, Ob, La, Lb, Wmp, bm, Yp + 256);

    // MLP layer 1 (BN-folded, relu): A=Yp [n][512], out Hp [n][512]
    gemm4w_kernel<<<dim3(NT / 128, 8), 256, 0, stream>>>(
        Yp, nullptr, W1p, b1f, Hp, nullptr, nullptr, nullptr, 512, 512, 512, 0, 1, 1.0f);
    // MLP layer 2: A=Hp, fp32 out [b][256][n]
    gemm4w_kernel<<<dim3(NT / 128, 4), 256, 0, stream>>>(
        Hp, nullptr, W2p, b2, nullptr, nullptr, nullptr, outp, 512, 512, 0, 2, 0, 1.0f);
}